// Round 9
// baseline (136.721 us; speedup 1.0000x reference)
//
#include <hip/hip_runtime.h>

// SpinConvSq2d via MFMA (bf16). Round 9: DIAGNOSTIC #2 + acc-union fix.
//  - Both roles share ONE set of six f32x16 accumulators (role0: S000,S011,
//    V0-2 in ac0-4; role1: T0-2,U0-2 in ac0-5) -> union liveness 96 VGPR,
//    removes the R8 spill risk from 11 live accumulators vs the 170-VGPR cap.
//  - Tap loop wrapped in runtime nrep=16 (accumulate 16x, output scales
//    folded by 1/16 -> exact). No re-staging, no extra barriers between reps;
//    opaque-zero per rep defeats LICM. dur = base + 15*loop_cost isolates the
//    tap-loop cost and surfaces the main kernel in rocprof top-5.
// Math identical to R3-R8 (refchecked, absmax 0.0156).

typedef __attribute__((ext_vector_type(8))) short short8;
typedef __attribute__((ext_vector_type(16))) float f32x16;
typedef __attribute__((ext_vector_type(4))) float float4v;

typedef __attribute__((address_space(3))) unsigned char lds_u8_t;
typedef const __attribute__((address_space(1))) unsigned char g_u8_t;

#define FEATT_BYTES (8u * 64u * 64u * 64u * 2u)   // 4 MB bf16 featT
#define BT_OFFSET   FEATT_BYTES                    // weight blob: 64000*2 B

#define MFMA32(A, B, C) __builtin_amdgcn_mfma_f32_32x32x16_bf16(A, B, C, 0, 0, 0)

__device__ __forceinline__ unsigned short f2bf(float f) {
    unsigned int u = __float_as_uint(f);
    return (unsigned short)((u + 0x7FFFu + ((u >> 16) & 1u)) >> 16);  // RNE
}

// ---------------- prep: featT [col][slot][y] bf16 + weight blob ----------------
__global__ __launch_bounds__(256) void prep_kernel(
    const float* __restrict__ feat,
    const float* __restrict__ W000, const float* __restrict__ W110,
    const float* __restrict__ W011, const float* __restrict__ W101,
    const float* __restrict__ W111,
    unsigned char* __restrict__ ws)
{
    int tid = threadIdx.x;
    int b = blockIdx.x;
    if (b < 512) {
        __shared__ float sf[64][68];          // 68-pad spreads banks
        size_t base = (size_t)b * 4096;       // floats (= shorts per column)
        #pragma unroll
        for (int i = 0; i < 4; ++i) {
            int e = tid + i * 256;            // float4 index 0..1023
            float4v v = *(const float4v*)(feat + base + (size_t)e * 4);
            int px = e >> 4;
            int c  = (e & 15) * 4;
            sf[px][c + 0] = v[0]; sf[px][c + 1] = v[1];
            sf[px][c + 2] = v[2]; sf[px][c + 3] = v[3];
        }
        __syncthreads();
        unsigned short* dst = (unsigned short*)ws + base;
        #pragma unroll
        for (int i = 0; i < 2; ++i) {
            int t = tid + i * 256;            // 0..511: s*64 + px
            int s = t >> 6, px = t & 63;
            short8 o;
            #pragma unroll
            for (int j = 0; j < 8; ++j) {
                int chp = s * 8 + j;
                int c = (chp < 16) ? chp : (16 + 3 * ((chp - 16) & 15) + ((chp - 16) >> 4));
                o[j] = (short)f2bf(sf[px][c]);
            }
            *(short8*)(dst + s * 512 + px * 8) = o;   // [slot][y] within column
        }
    } else {
        int t = (b - 512) * 256 + tid;        // 0..4095, need <4000
        if (t >= 4000) return;
        int a = t / 160, colv = t - a * 160;
        int arr = colv >> 5, w = colv & 31;
        const float* Wp = (arr == 0) ? W000 : (arr == 1) ? W011
                        : (arr == 2) ? W110 : (arr == 3) ? W101 : W111;
        unsigned short tmp[16];
        #pragma unroll
        for (int k = 0; k < 16; ++k) tmp[k] = f2bf(Wp[a * 512 + k * 32 + w]);
        unsigned short* d = (unsigned short*)(ws + BT_OFFSET) + (size_t)t * 16;
        *(short8*)(d)     = *(short8*)(tmp);
        *(short8*)(d + 8) = *(short8*)(tmp + 8);
    }
}

// ---------------- main MFMA kernel (nrep tap-loop diagnostic) ----------------
__global__ __launch_bounds__(256, 3) void spinconv_mfma_kernel(
    const unsigned char* __restrict__ featT8,
    const unsigned char* __restrict__ bt,
    const float* __restrict__ spin,
    float* __restrict__ out,
    int nrep)
{
    const float SH0f   = 0.28209479177387814f;
    const float CG110f = 0.5773502691896258f;
    const float CG111f = 0.7071067811865476f;
    const float A0f    = 0.035355339059327376f;
    const float A1f    = 0.028867513459481287f;

    __shared__ __align__(16) unsigned char fl[5 * 8 * 64 * 16]; // 40 KB; reused as rowbuf
    __shared__ float sbuf[2][16][64];                           // 8 KB: S011 handoff
    __shared__ float s_lds[192];                                // SH1*spin

    int tid = threadIdx.x;
    int b = blockIdx.x;
    int bid = ((b & 7) << 6) + (b >> 3);   // XCD-aware remap: n*64 + x
    int x = bid & 63;

    int lane = tid & 63;
    int wv4 = tid >> 6;            // 0..3

    // ---- async stage: 40 groups x 1KB, fully linear both sides ----
    #pragma unroll
    for (int i = 0; i < 10; ++i) {
        int g = wv4 * 10 + i;                 // g = dx*8 + s
        int dx = g >> 3;
        int X = (x + dx + 62) & 63;
        const unsigned char* src = featT8
            + (size_t)(bid - x + X) * 8192 + (g & 7) * 1024 + lane * 16;
        __builtin_amdgcn_global_load_lds((g_u8_t*)src, (lds_u8_t*)(fl + g * 1024), 16, 0, 0);
    }
    if (tid < 192) {
        s_lds[tid] = 0.4886025119029199f * spin[(size_t)bid * 192 + tid];
    }
    __syncthreads();

    int pair = wv4 >> 1;           // pixel half: 0 -> y 0-31, 1 -> y 32-63
    int role = wv4 & 1;            // 0: S000,S011,V; 1: T,U
    int col = lane & 31;           // N-col (w) and A-row (pixel within tile)
    int khalf = lane >> 5;         // K-half select
    int yb = pair << 5;
    int p0 = bid << 6;

    const unsigned char* bbase = bt + col * 32 + khalf * 16;
    float* rowbuf = (float*)fl;    // [64][128] floats after loops

    const float A0s = A0f / (float)nrep;
    const float A1s = A1f / (float)nrep;

    f32x16 zz;
    #pragma unroll
    for (int i = 0; i < 16; ++i) zz[i] = 0.f;

    // SHARED accumulator set (union across roles = 96 VGPR):
    // role0: ac0=S000 ac1=S011 ac2=V0 ac3=V1 ac4=V2 (ac5 unused)
    // role1: ac0=T0 ac1=T1 ac2=T2 ac3=U0 ac4=U1 ac5=U2
    f32x16 ac0 = zz, ac1 = zz, ac2 = zz, ac3 = zz, ac4 = zz, ac5 = zz;

    if (role == 0) {
        for (int rep = 0; rep < nrep; ++rep) {
            int opq = rep;                       // opaque 0: defeats LICM across reps
            asm volatile("" : "+v"(opq));
            opq -= rep;
            const unsigned char* flr = fl + opq;
            const unsigned char* btr = bbase + opq;

            short8 Bc0, Bc1, Bc2, Bn0, Bn1, Bn2;
            short8 Ax, Ac0, Ac1, Ac2, Nx, Nc0, Nc1, Nc2;

            auto loadB = [&](int a, short8& b0, short8& b1, short8& b2) {
                const unsigned char* p = btr + a * 5120;
                b0 = *(const short8*)(p);            // W000
                b1 = *(const short8*)(p + 1024);     // W011
                b2 = *(const short8*)(p + 2048);     // W110
            };
            auto loadA = [&](int a, short8& ax, short8& c0, short8& c1, short8& c2) {
                int ix = a / 5;
                int iy = a - ix * 5;
                int yn = (yb + col + iy + 62) & 63;
                const unsigned char* ab = flr + ix * 8192 + yn * 16;   // [slot][y]
                ax = *(const short8*)(ab + (0 + khalf) * 1024);
                c0 = *(const short8*)(ab + (2 + khalf) * 1024);
                c1 = *(const short8*)(ab + (4 + khalf) * 1024);
                c2 = *(const short8*)(ab + (6 + khalf) * 1024);
            };

            loadB(0, Bc0, Bc1, Bc2);
            loadA(0, Ax, Ac0, Ac1, Ac2);
            #pragma unroll
            for (int ap = 0; ap < 25; ap += 2) {
                if (ap + 1 < 25) { loadB(ap + 1, Bn0, Bn1, Bn2); loadA(ap + 1, Nx, Nc0, Nc1, Nc2); }
                __builtin_amdgcn_s_setprio(1);
                ac0 = MFMA32(Ax,  Bc0, ac0);
                ac1 = MFMA32(Ax,  Bc1, ac1);
                ac2 = MFMA32(Ac0, Bc2, ac2);
                ac3 = MFMA32(Ac1, Bc2, ac3);
                ac4 = MFMA32(Ac2, Bc2, ac4);
                __builtin_amdgcn_s_setprio(0);
                if (ap + 1 < 25) {
                    if (ap + 2 < 25) { loadB(ap + 2, Bc0, Bc1, Bc2); loadA(ap + 2, Ax, Ac0, Ac1, Ac2); }
                    __builtin_amdgcn_s_setprio(1);
                    ac0 = MFMA32(Nx,  Bn0, ac0);
                    ac1 = MFMA32(Nx,  Bn1, ac1);
                    ac2 = MFMA32(Nc0, Bn2, ac2);
                    ac3 = MFMA32(Nc1, Bn2, ac3);
                    ac4 = MFMA32(Nc2, Bn2, ac4);
                    __builtin_amdgcn_s_setprio(0);
                }
            }
        }
        // hand (nrep x) S011 to role B
        #pragma unroll
        for (int r = 0; r < 16; ++r) sbuf[pair][r][lane] = ac1[r];
    } else {
        for (int rep = 0; rep < nrep; ++rep) {
            int opq = rep;
            asm volatile("" : "+v"(opq));
            opq -= rep;
            const unsigned char* flr = fl + opq;
            const unsigned char* btr = bbase + opq;

            short8 Bc0, Bc1, Bn0, Bn1;
            short8 Ac0, Ac1, Ac2, Nc0, Nc1, Nc2;

            auto loadB = [&](int a, short8& b0, short8& b1) {
                const unsigned char* p = btr + a * 5120;
                b0 = *(const short8*)(p + 3072);     // W101
                b1 = *(const short8*)(p + 4096);     // W111
            };
            auto loadA = [&](int a, short8& c0, short8& c1, short8& c2) {
                int ix = a / 5;
                int iy = a - ix * 5;
                int yn = (yb + col + iy + 62) & 63;
                const unsigned char* ab = flr + ix * 8192 + yn * 16;   // [slot][y]
                c0 = *(const short8*)(ab + (2 + khalf) * 1024);
                c1 = *(const short8*)(ab + (4 + khalf) * 1024);
                c2 = *(const short8*)(ab + (6 + khalf) * 1024);
            };

            loadB(0, Bc0, Bc1);
            loadA(0, Ac0, Ac1, Ac2);
            #pragma unroll
            for (int ap = 0; ap < 25; ap += 2) {
                if (ap + 1 < 25) { loadB(ap + 1, Bn0, Bn1); loadA(ap + 1, Nc0, Nc1, Nc2); }
                __builtin_amdgcn_s_setprio(1);
                ac0 = MFMA32(Ac0, Bc0, ac0);
                ac3 = MFMA32(Ac0, Bc1, ac3);
                ac1 = MFMA32(Ac1, Bc0, ac1);
                ac4 = MFMA32(Ac1, Bc1, ac4);
                ac2 = MFMA32(Ac2, Bc0, ac2);
                ac5 = MFMA32(Ac2, Bc1, ac5);
                __builtin_amdgcn_s_setprio(0);
                if (ap + 1 < 25) {
                    if (ap + 2 < 25) { loadB(ap + 2, Bc0, Bc1); loadA(ap + 2, Ac0, Ac1, Ac2); }
                    __builtin_amdgcn_s_setprio(1);
                    ac0 = MFMA32(Nc0, Bn0, ac0);
                    ac3 = MFMA32(Nc0, Bn1, ac3);
                    ac1 = MFMA32(Nc1, Bn0, ac1);
                    ac4 = MFMA32(Nc1, Bn1, ac4);
                    ac2 = MFMA32(Nc2, Bn0, ac2);
                    ac5 = MFMA32(Nc2, Bn1, ac5);
                    __builtin_amdgcn_s_setprio(0);
                }
            }
        }
    }

    __syncthreads();   // loops done: fl dead, sbuf ready -> reuse fl as rowbuf

    // ---- deposit into LDS row buffer (C/D row = (r&3)+8*(r>>2)+4*khalf) ----
    if (role == 0) {
        #pragma unroll
        for (int r = 0; r < 16; ++r) {
            int row = (r & 3) + ((r >> 2) << 3) + (khalf << 2);
            int y = yb + row;
            float s0 = s_lds[y * 3 + 0];
            float s1 = s_lds[y * 3 + 1];
            float s2 = s_lds[y * 3 + 2];
            float o0 = A0s * (SH0f * ac0[r]
                     + CG110f * (s0 * ac2[r] + s1 * ac3[r] + s2 * ac4[r]));
            rowbuf[y * 128 + col] = o0;
        }
    } else {
        #pragma unroll
        for (int r = 0; r < 16; ++r) {
            int row = (r & 3) + ((r >> 2) << 3) + (khalf << 2);
            int y = yb + row;
            float s0 = s_lds[y * 3 + 0];
            float s1 = s_lds[y * 3 + 1];
            float s2 = s_lds[y * 3 + 2];
            float S011 = sbuf[pair][r][lane];
            float T0 = ac0[r], T1 = ac1[r], T2 = ac2[r];
            float U0 = ac3[r], U1 = ac4[r], U2 = ac5[r];
            float c0 = U1 * s2 - U2 * s1;
            float c1 = U2 * s0 - U0 * s2;
            float c2 = U0 * s1 - U1 * s0;
            float* rp = rowbuf + y * 128 + 32 + 3 * col;
            rp[0] = A1s * (s0 * S011 + SH0f * T0 + CG111f * c0);
            rp[1] = A1s * (s1 * S011 + SH0f * T1 + CG111f * c1);
            rp[2] = A1s * (s2 * S011 + SH0f * T2 + CG111f * c2);
        }
    }

    __syncthreads();

    // ---- cooperative contiguous store: 64 rows x 512B = 32KB, float4 lanes ----
    float* ob = out + (size_t)p0 * 128;
    #pragma unroll
    for (int i = 0; i < 8; ++i) {
        int e = (tid + (i << 8)) << 2;        // float offset, 16B-aligned
        *(float4v*)(ob + e) = *(const float4v*)(rowbuf + e);
    }
}

extern "C" void kernel_launch(void* const* d_in, const int* in_sizes, int n_in,
                              void* d_out, int out_size, void* d_ws, size_t ws_size,
                              hipStream_t stream) {
    const float* feat = (const float*)d_in[0];
    const float* spin = (const float*)d_in[1];
    const float* W000 = (const float*)d_in[2];
    const float* W110 = (const float*)d_in[3];
    const float* W011 = (const float*)d_in[4];
    const float* W101 = (const float*)d_in[5];
    const float* W111 = (const float*)d_in[6];
    float* out = (float*)d_out;
    unsigned char* ws = (unsigned char*)d_ws;

    hipLaunchKernelGGL(prep_kernel, dim3(528), dim3(256), 0, stream,
                       feat, W000, W110, W011, W101, W111, ws);
    hipLaunchKernelGGL(spinconv_mfma_kernel, dim3(512), dim3(256), 0, stream,
                       ws, ws + BT_OFFSET, spin, out, 16);
}

// Round 10
// 24.800 us; speedup vs baseline: 5.5129x; 5.5129x over previous
//
#include <hip/hip_runtime.h>

// SpinConvSq2d via MFMA (bf16). Round 10: disjoint-slot acc partition.
//  R9 diagnostic: loop 8.0us (MfmaUtil 53%, MFMA floor 3.7us), base 3.8us,
//  prep+launch 4.9us. Slack = duplicated LDS A-reads (roles shared c0-c2).
//  New partition reads each LDS slot ONCE per pair-tap (4 b128 vs 7):
//   role0: S000,S011,V0,T0,U0  (reads ax,c0; loads all 5 B mats)
//   role1: V1,V2,T1,T2,U1,U2   (reads c1,c2; loads W110,W101,W111)
//  Epilogue is linear in accs -> each role deposits PARTIAL outputs into
//  rowbuf (role0 writes, barrier, role1 +=). sbuf handoff eliminated.
//  role = (wv4&1)^(bid&1) mixes 5/6-MFMA waves across SIMDs.
// out0   = A0*(SH0*S000 + CG110*dot(s,V));  s = SH1*spin
// out1_i = A1*(s_i*S011 + SH0*T_i + CG111*cross(U,s)_i)

typedef __attribute__((ext_vector_type(8))) short short8;
typedef __attribute__((ext_vector_type(16))) float f32x16;
typedef __attribute__((ext_vector_type(4))) float float4v;

typedef __attribute__((address_space(3))) unsigned char lds_u8_t;
typedef const __attribute__((address_space(1))) unsigned char g_u8_t;

#define FEATT_BYTES (8u * 64u * 64u * 64u * 2u)   // 4 MB bf16 featT
#define BT_OFFSET   FEATT_BYTES                    // weight blob: 64000*2 B

#define MFMA32(A, B, C) __builtin_amdgcn_mfma_f32_32x32x16_bf16(A, B, C, 0, 0, 0)

__device__ __forceinline__ unsigned short f2bf(float f) {
    unsigned int u = __float_as_uint(f);
    return (unsigned short)((u + 0x7FFFu + ((u >> 16) & 1u)) >> 16);  // RNE
}

// ---------------- prep: featT [col][slot][y] bf16 + weight blob ----------------
__global__ __launch_bounds__(256) void prep_kernel(
    const float* __restrict__ feat,
    const float* __restrict__ W000, const float* __restrict__ W110,
    const float* __restrict__ W011, const float* __restrict__ W101,
    const float* __restrict__ W111,
    unsigned char* __restrict__ ws)
{
    int tid = threadIdx.x;
    int b = blockIdx.x;
    if (b < 512) {
        __shared__ float sf[64][68];          // 68-pad spreads banks
        size_t base = (size_t)b * 4096;       // floats (= shorts per column)
        #pragma unroll
        for (int i = 0; i < 4; ++i) {
            int e = tid + i * 256;            // float4 index 0..1023
            float4v v = *(const float4v*)(feat + base + (size_t)e * 4);
            int px = e >> 4;
            int c  = (e & 15) * 4;
            sf[px][c + 0] = v[0]; sf[px][c + 1] = v[1];
            sf[px][c + 2] = v[2]; sf[px][c + 3] = v[3];
        }
        __syncthreads();
        unsigned short* dst = (unsigned short*)ws + base;
        #pragma unroll
        for (int i = 0; i < 2; ++i) {
            int t = tid + i * 256;            // 0..511: s*64 + px
            int s = t >> 6, px = t & 63;
            short8 o;
            #pragma unroll
            for (int j = 0; j < 8; ++j) {
                int chp = s * 8 + j;
                int c = (chp < 16) ? chp : (16 + 3 * ((chp - 16) & 15) + ((chp - 16) >> 4));
                o[j] = (short)f2bf(sf[px][c]);
            }
            *(short8*)(dst + s * 512 + px * 8) = o;   // [slot][y] within column
        }
    } else {
        int t = (b - 512) * 256 + tid;        // 0..4095, need <4000
        if (t >= 4000) return;
        int a = t / 160, colv = t - a * 160;
        int arr = colv >> 5, w = colv & 31;
        const float* Wp = (arr == 0) ? W000 : (arr == 1) ? W011
                        : (arr == 2) ? W110 : (arr == 3) ? W101 : W111;
        unsigned short tmp[16];
        #pragma unroll
        for (int k = 0; k < 16; ++k) tmp[k] = f2bf(Wp[a * 512 + k * 32 + w]);
        unsigned short* d = (unsigned short*)(ws + BT_OFFSET) + (size_t)t * 16;
        *(short8*)(d)     = *(short8*)(tmp);
        *(short8*)(d + 8) = *(short8*)(tmp + 8);
    }
}

// ---------------- main MFMA kernel ----------------
__global__ __launch_bounds__(256, 2) void spinconv_mfma_kernel(
    const unsigned char* __restrict__ featT8,
    const unsigned char* __restrict__ bt,
    const float* __restrict__ spin,
    float* __restrict__ out)
{
    const float SH0f   = 0.28209479177387814f;
    const float CG110f = 0.5773502691896258f;
    const float CG111f = 0.7071067811865476f;
    const float A0f    = 0.035355339059327376f;
    const float A1f    = 0.028867513459481287f;

    __shared__ __align__(16) unsigned char fl[5 * 8 * 64 * 16]; // 40 KB [dx][slot][y]; reused as rowbuf
    __shared__ float s_lds[192];                                // SH1*spin

    int tid = threadIdx.x;
    int b = blockIdx.x;
    int bid = ((b & 7) << 6) + (b >> 3);   // XCD-aware remap: n*64 + x
    int x = bid & 63;

    int lane = tid & 63;
    int wv4 = tid >> 6;            // 0..3

    // ---- async stage: 40 groups x 1KB, fully linear both sides ----
    #pragma unroll
    for (int i = 0; i < 10; ++i) {
        int g = wv4 * 10 + i;                 // g = dx*8 + s
        int dx = g >> 3;
        int X = (x + dx + 62) & 63;
        const unsigned char* src = featT8
            + (size_t)(bid - x + X) * 8192 + (g & 7) * 1024 + lane * 16;
        __builtin_amdgcn_global_load_lds((g_u8_t*)src, (lds_u8_t*)(fl + g * 1024), 16, 0, 0);
    }
    if (tid < 192) {
        s_lds[tid] = 0.4886025119029199f * spin[(size_t)bid * 192 + tid];
    }
    __syncthreads();

    int pair = wv4 >> 1;               // pixel half: 0 -> y 0-31, 1 -> y 32-63
    int role = (wv4 & 1) ^ (bid & 1);  // SIMD-mixed role assignment
    int col = lane & 31;               // N-col (w) and A-row (pixel within tile)
    int khalf = lane >> 5;             // K-half select
    int yb = pair << 5;
    int p0 = bid << 6;

    const unsigned char* bbase = bt + col * 32 + khalf * 16;
    float* rowbuf = (float*)fl;        // [64][128] floats after loops

    f32x16 zz;
    #pragma unroll
    for (int i = 0; i < 16; ++i) zz[i] = 0.f;

    // shared acc set (union = 6 accs):
    // role0: ac0=S000 ac1=S011 ac2=V0 ac3=T0 ac4=U0
    // role1: ac0=V1 ac1=V2 ac2=T1 ac3=T2 ac4=U1 ac5=U2
    f32x16 ac0 = zz, ac1 = zz, ac2 = zz, ac3 = zz, ac4 = zz, ac5 = zz;

    if (role == 0) {
        short8 B0c, B1c, B2c, B3c, B4c, B0n, B1n, B2n, B3n, B4n;
        short8 Axc, C0c, Axn, C0n;

        auto loadB = [&](int a, short8& b0, short8& b1, short8& b2, short8& b3, short8& b4) {
            const unsigned char* p = bbase + a * 5120;
            b0 = *(const short8*)(p);            // W000
            b1 = *(const short8*)(p + 1024);     // W011
            b2 = *(const short8*)(p + 2048);     // W110
            b3 = *(const short8*)(p + 3072);     // W101
            b4 = *(const short8*)(p + 4096);     // W111
        };
        auto loadA = [&](int a, short8& ax, short8& c0) {
            int ix = a / 5;
            int iy = a - ix * 5;
            int yn = (yb + col + iy + 62) & 63;
            const unsigned char* ab = fl + ix * 8192 + yn * 16;   // [slot][y]
            ax = *(const short8*)(ab + (0 + khalf) * 1024);
            c0 = *(const short8*)(ab + (2 + khalf) * 1024);
        };

        loadB(0, B0c, B1c, B2c, B3c, B4c);
        loadA(0, Axc, C0c);
        #pragma unroll
        for (int ap = 0; ap < 25; ap += 2) {
            if (ap + 1 < 25) { loadB(ap + 1, B0n, B1n, B2n, B3n, B4n); loadA(ap + 1, Axn, C0n); }
            __builtin_amdgcn_s_setprio(1);
            ac0 = MFMA32(Axc, B0c, ac0);   // S000
            ac1 = MFMA32(Axc, B1c, ac1);   // S011
            ac2 = MFMA32(C0c, B2c, ac2);   // V0
            ac3 = MFMA32(C0c, B3c, ac3);   // T0
            ac4 = MFMA32(C0c, B4c, ac4);   // U0
            __builtin_amdgcn_s_setprio(0);
            if (ap + 1 < 25) {
                if (ap + 2 < 25) { loadB(ap + 2, B0c, B1c, B2c, B3c, B4c); loadA(ap + 2, Axc, C0c); }
                __builtin_amdgcn_s_setprio(1);
                ac0 = MFMA32(Axn, B0n, ac0);
                ac1 = MFMA32(Axn, B1n, ac1);
                ac2 = MFMA32(C0n, B2n, ac2);
                ac3 = MFMA32(C0n, B3n, ac3);
                ac4 = MFMA32(C0n, B4n, ac4);
                __builtin_amdgcn_s_setprio(0);
            }
        }
    } else {
        short8 B2c, B3c, B4c, B2n, B3n, B4n;
        short8 C1c, C2c, C1n, C2n;

        auto loadB = [&](int a, short8& b2, short8& b3, short8& b4) {
            const unsigned char* p = bbase + a * 5120;
            b2 = *(const short8*)(p + 2048);     // W110
            b3 = *(const short8*)(p + 3072);     // W101
            b4 = *(const short8*)(p + 4096);     // W111
        };
        auto loadA = [&](int a, short8& c1, short8& c2) {
            int ix = a / 5;
            int iy = a - ix * 5;
            int yn = (yb + col + iy + 62) & 63;
            const unsigned char* ab = fl + ix * 8192 + yn * 16;   // [slot][y]
            c1 = *(const short8*)(ab + (4 + khalf) * 1024);
            c2 = *(const short8*)(ab + (6 + khalf) * 1024);
        };

        loadB(0, B2c, B3c, B4c);
        loadA(0, C1c, C2c);
        #pragma unroll
        for (int ap = 0; ap < 25; ap += 2) {
            if (ap + 1 < 25) { loadB(ap + 1, B2n, B3n, B4n); loadA(ap + 1, C1n, C2n); }
            __builtin_amdgcn_s_setprio(1);
            ac0 = MFMA32(C1c, B2c, ac0);   // V1
            ac1 = MFMA32(C2c, B2c, ac1);   // V2
            ac2 = MFMA32(C1c, B3c, ac2);   // T1
            ac3 = MFMA32(C2c, B3c, ac3);   // T2
            ac4 = MFMA32(C1c, B4c, ac4);   // U1
            ac5 = MFMA32(C2c, B4c, ac5);   // U2
            __builtin_amdgcn_s_setprio(0);
            if (ap + 1 < 25) {
                if (ap + 2 < 25) { loadB(ap + 2, B2c, B3c, B4c); loadA(ap + 2, C1c, C2c); }
                __builtin_amdgcn_s_setprio(1);
                ac0 = MFMA32(C1n, B2n, ac0);
                ac1 = MFMA32(C2n, B2n, ac1);
                ac2 = MFMA32(C1n, B3n, ac2);
                ac3 = MFMA32(C2n, B3n, ac3);
                ac4 = MFMA32(C1n, B4n, ac4);
                ac5 = MFMA32(C2n, B4n, ac5);
                __builtin_amdgcn_s_setprio(0);
            }
        }
    }

    __syncthreads();   // tap loops done: fl dead -> reuse as rowbuf

    // ---- partial deposits (C/D row = (r&3)+8*(r>>2)+4*khalf); epilogue is
    //      linear in accs so role partials simply add ----
    if (role == 0) {
        #pragma unroll
        for (int r = 0; r < 16; ++r) {
            int row = (r & 3) + ((r >> 2) << 3) + (khalf << 2);
            int y = yb + row;
            float s0 = s_lds[y * 3 + 0];
            float s1 = s_lds[y * 3 + 1];
            float s2 = s_lds[y * 3 + 2];
            float S000 = ac0[r], S011 = ac1[r];
            float V0 = ac2[r], T0 = ac3[r], U0 = ac4[r];
            rowbuf[y * 128 + col] = A0f * (SH0f * S000 + CG110f * s0 * V0);
            float* rp = rowbuf + y * 128 + 32 + 3 * col;
            rp[0] = A1f * (s0 * S011 + SH0f * T0);
            rp[1] = A1f * (s1 * S011 - CG111f * U0 * s2);
            rp[2] = A1f * (s2 * S011 + CG111f * U0 * s1);
        }
    }
    __syncthreads();
    if (role == 1) {
        #pragma unroll
        for (int r = 0; r < 16; ++r) {
            int row = (r & 3) + ((r >> 2) << 3) + (khalf << 2);
            int y = yb + row;
            float s0 = s_lds[y * 3 + 0];
            float s1 = s_lds[y * 3 + 1];
            float s2 = s_lds[y * 3 + 2];
            float V1 = ac0[r], V2 = ac1[r];
            float T1 = ac2[r], T2 = ac3[r];
            float U1 = ac4[r], U2 = ac5[r];
            rowbuf[y * 128 + col] += A0f * CG110f * (s1 * V1 + s2 * V2);
            float* rp = rowbuf + y * 128 + 32 + 3 * col;
            rp[0] += A1f * CG111f * (U1 * s2 - U2 * s1);
            rp[1] += A1f * (SH0f * T1 + CG111f * U2 * s0);
            rp[2] += A1f * (SH0f * T2 - CG111f * U1 * s0);
        }
    }
    __syncthreads();

    // ---- cooperative contiguous store: 64 rows x 512B = 32KB, float4 lanes ----
    float* ob = out + (size_t)p0 * 128;
    #pragma unroll
    for (int i = 0; i < 8; ++i) {
        int e = (tid + (i << 8)) << 2;        // float offset, 16B-aligned
        *(float4v*)(ob + e) = *(const float4v*)(rowbuf + e);
    }
}

extern "C" void kernel_launch(void* const* d_in, const int* in_sizes, int n_in,
                              void* d_out, int out_size, void* d_ws, size_t ws_size,
                              hipStream_t stream) {
    const float* feat = (const float*)d_in[0];
    const float* spin = (const float*)d_in[1];
    const float* W000 = (const float*)d_in[2];
    const float* W110 = (const float*)d_in[3];
    const float* W011 = (const float*)d_in[4];
    const float* W101 = (const float*)d_in[5];
    const float* W111 = (const float*)d_in[6];
    float* out = (float*)d_out;
    unsigned char* ws = (unsigned char*)d_ws;

    hipLaunchKernelGGL(prep_kernel, dim3(528), dim3(256), 0, stream,
                       feat, W000, W110, W011, W101, W111, ws);
    hipLaunchKernelGGL(spinconv_mfma_kernel, dim3(512), dim3(256), 0, stream,
                       ws, ws + BT_OFFSET, spin, out);
}